// Round 4
// baseline (944.364 us; speedup 1.0000x reference)
//
#include <hip/hip_runtime.h>

#define NP 32
#define NROWS 65536

#if __has_builtin(__builtin_amdgcn_rcpf)
#define FAST_RCP(x) __builtin_amdgcn_rcpf(x)
#else
#define FAST_RCP(x) (1.0f / (x))
#endif

__device__ __forceinline__ float fast_tanh(float v) {
    float xc = fminf(fmaxf(v, -9.0f), 9.0f);
    float e = __expf(2.0f * xc);
    return (e - 1.0f) * FAST_RCP(e + 1.0f);
}

// ---------------- repetition macros (straight-line code generation) --------
#define REP8(M) M(0) M(1) M(2) M(3) M(4) M(5) M(6) M(7)
#define REP16(M) REP8(M) M(8) M(9) M(10) M(11) M(12) M(13) M(14) M(15)
#define REP32(M) REP16(M) M(16) M(17) M(18) M(19) M(20) M(21) M(22) M(23) \
                 M(24) M(25) M(26) M(27) M(28) M(29) M(30) M(31)
#define REP64(M) REP32(M) M(32) M(33) M(34) M(35) M(36) M(37) M(38) M(39) \
                 M(40) M(41) M(42) M(43) M(44) M(45) M(46) M(47) \
                 M(48) M(49) M(50) M(51) M(52) M(53) M(54) M(55) \
                 M(56) M(57) M(58) M(59) M(60) M(61) M(62) M(63)

// One FMA term: S##i pastes the bank prefix with a literal index -> named SSA
// scalar. No arrays exist anywhere, so scratch demotion is impossible.
#define FA(W, S, A, i) fmaf((W)[i], S##i, (A))

#define D8(W, S, A, i0, i1, i2, i3, i4, i5, i6, i7)                          \
    FA(W, S, FA(W, S, FA(W, S, FA(W, S, FA(W, S, FA(W, S, FA(W, S,          \
    FA(W, S, A, i0), i1), i2), i3), i4), i5), i6), i7)

#define D7HI(W, S, A)                                                        \
    FA(W, S, FA(W, S, FA(W, S, FA(W, S, FA(W, S, FA(W, S,                   \
    FA(W, S, A, 24), 25), 26), 27), 28), 29), 30)

#define DOT8(W, S, A) D8(W, S, A, 0, 1, 2, 3, 4, 5, 6, 7)
#define DOT16(W, S, A) D8(W, S, DOT8(W, S, A), 8, 9, 10, 11, 12, 13, 14, 15)
// 2+ independent partial chains per dot: ~16-term chains, summed at the end.
#define DOT32(W, S, A)                                                       \
    (D8(W, S, D8(W, S, 0.0f, 16, 17, 18, 19, 20, 21, 22, 23),               \
        24, 25, 26, 27, 28, 29, 30, 31) + DOT16(W, S, A))
#define DOT31(W, S, A)                                                       \
    (D7HI(W, S, D8(W, S, 0.0f, 16, 17, 18, 19, 20, 21, 22, 23))             \
     + DOT16(W, S, A))
#define DOT64(W, S, A)                                                       \
    (D8(W, S, D8(W, S, D8(W, S, D8(W, S, 0.0f,                              \
        32, 33, 34, 35, 36, 37, 38, 39), 40, 41, 42, 43, 44, 45, 46, 47),   \
        48, 49, 50, 51, 52, 53, 54, 55), 56, 57, 58, 59, 60, 61, 62, 63)    \
     + DOT32(W, S, A))

__global__ __launch_bounds__(256, 3) void fused_mlp(
    const float* __restrict__ xg,
    const float* __restrict__ Wa1, const float* __restrict__ ba1,
    const float* __restrict__ Wa2, const float* __restrict__ ba2,
    const float* __restrict__ Wa3, const float* __restrict__ ba3,
    const float* __restrict__ Wa4, const float* __restrict__ ba4,
    const float* __restrict__ Wa5, const float* __restrict__ ba5,
    const float* __restrict__ Wb1, const float* __restrict__ bb1,
    const float* __restrict__ Wb2, const float* __restrict__ bb2,
    const float* __restrict__ Wb3, const float* __restrict__ bb3,
    const float* __restrict__ Wb4, const float* __restrict__ bb4,
    const float* __restrict__ Wb5, const float* __restrict__ bb5,
    const float* __restrict__ Wb6, const float* __restrict__ bb6,
    float* __restrict__ out) {
    const int p = blockIdx.y;                       // feature (block-uniform)
    const int n = blockIdx.x * 256 + threadIdx.x;   // row

    // uniform weight bases -> constant-offset scalar loads
    const float* Wb1p = Wb1 + p * 1984; const float* bb1p = bb1 + p * 64;
    const float* Wb2p = Wb2 + p * 2048; const float* bb2p = bb2 + p * 32;
    const float* Wb3p = Wb3 + p * 1024; const float* bb3p = bb3 + p * 32;
    const float* Wb4p = Wb4 + p * 512;  const float* bb4p = bb4 + p * 16;
    const float* Wb5p = Wb5 + p * 128;  const float* bb5p = bb5 + p * 8;
    const float* Wb6p = Wb6 + p * 8;    const float* bb6p = bb6 + p;
    const float* Wa1p = Wa1 + p * 64;   const float* ba1p = ba1 + p * 64;
    const float* Wa2p = Wa2 + p * 2048; const float* ba2p = ba2 + p * 32;
    const float* Wa3p = Wa3 + p * 512;  const float* ba3p = ba3 + p * 16;
    const float* Wa4p = Wa4 + p * 128;  const float* ba4p = ba4 + p * 8;
    const float* Wa5p = Wa5 + p * 8;    const float* ba5p = ba5 + p;

    // ---- row load: 8 aligned float4, all named values ---------------------
    const float4* xrow = reinterpret_cast<const float4*>(xg + n * NP);
    const float4 q0 = xrow[0], q1 = xrow[1], q2 = xrow[2], q3 = xrow[3];
    const float4 q4 = xrow[4], q5 = xrow[5], q6 = xrow[6], q7 = xrow[7];

    // leave-one-out gather into named x0..x30; (f < p) is block-uniform
    const float x0  = (0  < p) ? q0.x : q0.y;
    const float x1  = (1  < p) ? q0.y : q0.z;
    const float x2  = (2  < p) ? q0.z : q0.w;
    const float x3  = (3  < p) ? q0.w : q1.x;
    const float x4  = (4  < p) ? q1.x : q1.y;
    const float x5  = (5  < p) ? q1.y : q1.z;
    const float x6  = (6  < p) ? q1.z : q1.w;
    const float x7  = (7  < p) ? q1.w : q2.x;
    const float x8  = (8  < p) ? q2.x : q2.y;
    const float x9  = (9  < p) ? q2.y : q2.z;
    const float x10 = (10 < p) ? q2.z : q2.w;
    const float x11 = (11 < p) ? q2.w : q3.x;
    const float x12 = (12 < p) ? q3.x : q3.y;
    const float x13 = (13 < p) ? q3.y : q3.z;
    const float x14 = (14 < p) ? q3.z : q3.w;
    const float x15 = (15 < p) ? q3.w : q4.x;
    const float x16 = (16 < p) ? q4.x : q4.y;
    const float x17 = (17 < p) ? q4.y : q4.z;
    const float x18 = (18 < p) ? q4.z : q4.w;
    const float x19 = (19 < p) ? q4.w : q5.x;
    const float x20 = (20 < p) ? q5.x : q5.y;
    const float x21 = (21 < p) ? q5.y : q5.z;
    const float x22 = (22 < p) ? q5.z : q5.w;
    const float x23 = (23 < p) ? q5.w : q6.x;
    const float x24 = (24 < p) ? q6.x : q6.y;
    const float x25 = (25 < p) ? q6.y : q6.z;
    const float x26 = (26 < p) ? q6.z : q6.w;
    const float x27 = (27 < p) ? q6.w : q7.x;
    const float x28 = (28 < p) ? q7.x : q7.y;
    const float x29 = (29 < p) ? q7.y : q7.z;
    const float x30 = (30 < p) ? q7.z : q7.w;
    const float xa = xg[n * NP + p];   // scalar pick, L1-hot

    // ---- register banks: named scalars only --------------------------------
#define DV(i) float v##i;
    REP64(DV)
#define DU(i) float u##i;
    REP32(DU)

    // ============ Encoder B: 31 ->64(relu) ->32(th) ->32(th) ->16(th) ->8 ->1
#define B1(o) v##o = fmaxf(DOT31(Wb1p + (o) * 31, x, bb1p[(o)]), 0.0f);
    REP64(B1)
#define B2(o) u##o = fast_tanh(DOT64(Wb2p + (o) * 64, v, bb2p[(o)]));
    REP32(B2)
#define B3(o) v##o = fast_tanh(DOT32(Wb3p + (o) * 32, u, bb3p[(o)]));
    REP32(B3)
#define B4(o) u##o = fast_tanh(DOT32(Wb4p + (o) * 32, v, bb4p[(o)]));
    REP16(B4)
#define B5(o) v##o = DOT16(Wb5p + (o) * 16, u, bb5p[(o)]);
    REP8(B5)
    const float bv = DOT8(Wb6p, v, bb6p[0]);

    // ============ Encoder A: 1 ->64(relu) ->32(th) ->16(th) ->8(th) ->1 =====
#define A1(o) v##o = fmaxf(fmaf(Wa1p[(o)], xa, ba1p[(o)]), 0.0f);
    REP64(A1)
#define A2(o) u##o = fast_tanh(DOT64(Wa2p + (o) * 64, v, ba2p[(o)]));
    REP32(A2)
#define A3(o) v##o = fast_tanh(DOT32(Wa3p + (o) * 32, u, ba3p[(o)]));
    REP16(A3)
#define A4(o) u##o = fast_tanh(DOT16(Wa4p + (o) * 16, v, ba4p[(o)]));
    REP8(A4)
    const float av = DOT8(Wa5p, u, ba5p[0]);

    // out[n, 2p]=a, out[n, 2p+1]=b (single aligned float2 store)
    reinterpret_cast<float2*>(out)[n * NP + p] = make_float2(av, bv);
}

extern "C" void kernel_launch(void* const* d_in, const int* in_sizes, int n_in,
                              void* d_out, int out_size, void* d_ws,
                              size_t ws_size, hipStream_t stream) {
    const float* x   = (const float*)d_in[0];
    const float* Wa1 = (const float*)d_in[1];
    const float* ba1 = (const float*)d_in[2];
    const float* Wa2 = (const float*)d_in[3];
    const float* ba2 = (const float*)d_in[4];
    const float* Wa3 = (const float*)d_in[5];
    const float* ba3 = (const float*)d_in[6];
    const float* Wa4 = (const float*)d_in[7];
    const float* ba4 = (const float*)d_in[8];
    const float* Wa5 = (const float*)d_in[9];
    const float* ba5 = (const float*)d_in[10];
    const float* Wb1 = (const float*)d_in[11];
    const float* bb1 = (const float*)d_in[12];
    const float* Wb2 = (const float*)d_in[13];
    const float* bb2 = (const float*)d_in[14];
    const float* Wb3 = (const float*)d_in[15];
    const float* bb3 = (const float*)d_in[16];
    const float* Wb4 = (const float*)d_in[17];
    const float* bb4 = (const float*)d_in[18];
    const float* Wb5 = (const float*)d_in[19];
    const float* bb5 = (const float*)d_in[20];
    const float* Wb6 = (const float*)d_in[21];
    const float* bb6 = (const float*)d_in[22];

    dim3 grid(NROWS / 256, NP);
    fused_mlp<<<grid, 256, 0, stream>>>(
        x, Wa1, ba1, Wa2, ba2, Wa3, ba3, Wa4, ba4, Wa5, ba5,
        Wb1, bb1, Wb2, bb2, Wb3, bb3, Wb4, bb4, Wb5, bb5, Wb6, bb6,
        (float*)d_out);
}

// Round 5
// 302.210 us; speedup vs baseline: 3.1249x; 3.1249x over previous
//
#include <hip/hip_runtime.h>

#define NP 32
#define NROWS 65536

typedef _Float16 f16x8 __attribute__((ext_vector_type(8)));
typedef _Float16 f16x4 __attribute__((ext_vector_type(4)));
typedef float    f32x4 __attribute__((ext_vector_type(4)));

#if __has_builtin(__builtin_amdgcn_rcpf)
#define FAST_RCP(x) __builtin_amdgcn_rcpf(x)
#else
#define FAST_RCP(x) (1.0f / (x))
#endif

__device__ __forceinline__ float fast_tanh(float v) {
    float xc = fminf(fmaxf(v, -9.0f), 9.0f);
    float e = __expf(2.0f * xc);
    return (e - 1.0f) * FAST_RCP(e + 1.0f);
}

// ---------------- prepacked weight storage (device globals, ~1.9 MB) -------
// 18 MFMA steps per p: B1:s0-3  B2:s4-7  B3:s8-9  B4:s10  B5:s11
//                      A2:s12-15  A3:s16  A4:s17      (order: for Mt, for ks)
// A-frag layout assumed: A[row=lane&15][k=8*(lane>>4)+e], e=0..7.
// 14 bias steps (C-layout: out=16*Mt+4*(lane>>4)+j): B1:0-3 B2:4-5 B3:6-7
//                      B4:8 B5:9 A2:10-11 A3:12 A4:13
__device__ __align__(16) _Float16 g_frag[NP][18 * 2 * 64 * 8]; // hi/lo pairs
__device__ __align__(16) float    g_bias[NP][14 * 64 * 4];
__device__ __align__(16) float    g_a1w [NP][4 * 64 * 4];
__device__ __align__(16) float    g_a1b [NP][4 * 64 * 4];
__device__ __align__(16) float    g_fin [NP][32]; // Wb6[0..7], bb6[8], Wa5[9..16], ba5[17]

__global__ void prep_frags(
    const float* __restrict__ Wa1, const float* __restrict__ ba1,
    const float* __restrict__ Wa2, const float* __restrict__ ba2,
    const float* __restrict__ Wa3, const float* __restrict__ ba3,
    const float* __restrict__ Wa4, const float* __restrict__ ba4,
    const float* __restrict__ Wa5, const float* __restrict__ ba5,
    const float* __restrict__ Wb1, const float* __restrict__ bb1,
    const float* __restrict__ Wb2, const float* __restrict__ bb2,
    const float* __restrict__ Wb3, const float* __restrict__ bb3,
    const float* __restrict__ Wb4, const float* __restrict__ bb4,
    const float* __restrict__ Wb5, const float* __restrict__ bb5,
    const float* __restrict__ Wb6, const float* __restrict__ bb6) {
    const int p = blockIdx.x;
    const int l = threadIdx.x;          // 0..63
    const int g = l >> 4, q = l & 15;

    const int sw[18]  = {0,0,0,0, 1,1,1,1, 2,2, 3, 4, 5,5,5,5, 6, 7};
    const int sMt[18] = {0,1,2,3, 0,0,1,1, 0,1, 0, 0, 0,0,1,1, 0, 0};
    const int sks[18] = {0,0,0,0, 0,1,0,1, 0,0, 0, 0, 0,1,0,1, 0, 0};
    const int OO[8] = {64,32,32,16, 8,32,16, 8};
    const int II[8] = {31,64,32,32,16,64,32,16};
    const float* WS[8] = {Wb1 + p*1984, Wb2 + p*2048, Wb3 + p*1024,
                          Wb4 + p*512,  Wb5 + p*128,
                          Wa2 + p*2048, Wa3 + p*512,  Wa4 + p*128};
    for (int s = 0; s < 18; ++s) {
        const int w = sw[s], O = OO[w], I = II[w];
        const float* W = WS[w];
        for (int e = 0; e < 8; ++e) {
            const int kk = 32*sks[s] + 8*g + e;   // K index
            const int o  = 16*sMt[s] + q;         // out (= A row)
            const float wv = (o < O && kk < I) ? W[o*I + kk] : 0.0f;
            const _Float16 hi = (_Float16)wv;
            const _Float16 lo = (_Float16)(wv - (float)hi);
            g_frag[p][((s*2 + 0)*64 + l)*8 + e] = hi;
            g_frag[p][((s*2 + 1)*64 + l)*8 + e] = lo;
        }
    }
    const int bw[14]  = {0,0,0,0, 1,1, 2,2, 3, 4, 5,5, 6, 7};
    const int bMt[14] = {0,1,2,3, 0,1, 0,1, 0, 0, 0,1, 0, 0};
    const float* BS[8] = {bb1 + p*64, bb2 + p*32, bb3 + p*32, bb4 + p*16,
                          bb5 + p*8,  ba2 + p*32, ba3 + p*16, ba4 + p*8};
    for (int bs = 0; bs < 14; ++bs) {
        const int w = bw[bs];
        for (int j = 0; j < 4; ++j) {
            const int o = 16*bMt[bs] + 4*g + j;   // C-layout out index
            g_bias[p][(bs*64 + l)*4 + j] = (o < OO[w]) ? BS[w][o] : 0.0f;
        }
    }
    for (int Mt = 0; Mt < 4; ++Mt)
        for (int j = 0; j < 4; ++j) {
            const int o = 16*Mt + 4*g + j;
            g_a1w[p][(Mt*64 + l)*4 + j] = Wa1[p*64 + o];
            g_a1b[p][(Mt*64 + l)*4 + j] = ba1[p*64 + o];
        }
    if (l == 0) {
        for (int e = 0; e < 8; ++e) {
            g_fin[p][e]     = Wb6[p*8 + e];
            g_fin[p][9 + e] = Wa5[p*8 + e];
        }
        g_fin[p][8]  = bb6[p];
        g_fin[p][17] = ba5[p];
    }
}

// ---------------- main kernel ----------------------------------------------
// Wave = 32 rows (2 tiles of 16). acts ping-pong in private LDS slices,
// [32 rows][stride 68 halves] (≤2-way bank aliasing = free). No barriers.
#define STRD 68

template <int KS>
__device__ __forceinline__ void read_bf(const _Float16* src, f16x8 (&bf)[2][2],
                                        int q, int g) {
#pragma unroll
    for (int t = 0; t < 2; ++t)
#pragma unroll
        for (int ks = 0; ks < KS; ++ks) {
            const _Float16* a = src + (16*t + q)*STRD + 32*ks + 8*g;
            const f16x4 v0 = *(const f16x4*)(a);
            const f16x4 v1 = *(const f16x4*)(a + 4);
            bf[t][ks] = __builtin_shufflevector(v0, v1, 0,1,2,3,4,5,6,7);
        }
}

// C[out=16Mt+4g+j][n=16t+q] += (Whi+Wlo) . B  ; then bias+act -> dst plane
template <int MT, int KS, int ACT, bool ZPAD>
__device__ __forceinline__ void mfma_block(const _Float16* __restrict__ frag,
                                           const float* __restrict__ bias,
                                           int s0, int b0,
                                           const f16x8 (&bf)[2][2],
                                           _Float16* dst, int q, int g, int l) {
#pragma unroll
    for (int Mt = 0; Mt < MT; ++Mt) {
        f32x4 a0 = {0.f,0.f,0.f,0.f}, a1 = {0.f,0.f,0.f,0.f};
#pragma unroll
        for (int ks = 0; ks < KS; ++ks) {
            const int s = s0 + Mt*KS + ks;
            const f16x8 whi = *(const f16x8*)(frag + ((s*2 + 0)*64 + l)*8);
            const f16x8 wlo = *(const f16x8*)(frag + ((s*2 + 1)*64 + l)*8);
            a0 = __builtin_amdgcn_mfma_f32_16x16x32_f16(wlo, bf[0][ks], a0, 0,0,0);
            a0 = __builtin_amdgcn_mfma_f32_16x16x32_f16(whi, bf[0][ks], a0, 0,0,0);
            a1 = __builtin_amdgcn_mfma_f32_16x16x32_f16(wlo, bf[1][ks], a1, 0,0,0);
            a1 = __builtin_amdgcn_mfma_f32_16x16x32_f16(whi, bf[1][ks], a1, 0,0,0);
        }
        const f32x4 b4 = *(const f32x4*)(bias + ((b0 + Mt)*64 + l)*4);
#pragma unroll
        for (int t = 0; t < 2; ++t) {
            const f32x4 av = t ? a1 : a0;
            f16x4 o4;
#pragma unroll
            for (int j = 0; j < 4; ++j) {
                float c = av[j] + b4[j];
                if (ACT == 1) c = fmaxf(c, 0.0f);
                if (ACT == 2) c = fast_tanh(c);
                o4[j] = (_Float16)c;
            }
            *(f16x4*)(dst + (16*t + q)*STRD + 16*Mt + 4*g) = o4;
        }
    }
    if (ZPAD) {   // zero k=16..31 so next layer can read a padded K=32
        const f16x4 z = {(_Float16)0, (_Float16)0, (_Float16)0, (_Float16)0};
#pragma unroll
        for (int t = 0; t < 2; ++t)
            *(f16x4*)(dst + (16*t + q)*STRD + 16 + 4*g) = z;
    }
}

__global__ __launch_bounds__(256, 4) void mlp_mfma(
    const float* __restrict__ x, float* __restrict__ out) {
    __shared__ __align__(16) _Float16 lds[4][2][32 * STRD];
    const int p  = blockIdx.y;
    const int wv = threadIdx.x >> 6;
    const int l  = threadIdx.x & 63;
    const int g  = l >> 4, q = l & 15;
    const int row0 = blockIdx.x * 128 + wv * 32;

    _Float16* pl0 = &lds[wv][0][0];
    _Float16* pl1 = &lds[wv][1][0];
    const _Float16* frag = g_frag[p];
    const float*    bias = g_bias[p];
    const float*    fin  = g_fin[p];

    f16x8 bf[2][2];

    // ---- B1 B-frag straight from x (leave-one-out, k=31 padded to 0) ------
#pragma unroll
    for (int t = 0; t < 2; ++t) {
        const int grow = row0 + 16*t + q;
        const float* xr = x + grow * NP;
#pragma unroll
        for (int e = 0; e < 8; ++e) {
            const int k = 8*g + e;
            const int f = (k < 31) ? (k + (k >= p ? 1 : 0)) : 0; // in-bounds
            const float xv = xr[f];
            bf[t][0][e] = (_Float16)((k < 31) ? xv : 0.0f);
        }
    }
    // B1: 31->64 relu
    mfma_block<4,1,1,false>(frag, bias,  0,  0, bf, pl0, q, g, l);
    read_bf<2>(pl0, bf, q, g);
    // B2: 64->32 tanh
    mfma_block<2,2,2,false>(frag, bias,  4,  4, bf, pl1, q, g, l);
    read_bf<1>(pl1, bf, q, g);
    // B3: 32->32 tanh
    mfma_block<2,1,2,false>(frag, bias,  8,  6, bf, pl0, q, g, l);
    read_bf<1>(pl0, bf, q, g);
    // B4: 32->16 tanh (+zero-pad K to 32)
    mfma_block<1,1,2,true >(frag, bias, 10,  8, bf, pl1, q, g, l);
    read_bf<1>(pl1, bf, q, g);
    // B5: 16->8 linear (padded rows produce zeros)
    mfma_block<1,1,0,false>(frag, bias, 11,  9, bf, pl0, q, g, l);

    // B6: 8->1 on VALU (all lane-groups compute redundantly; no divergence)
    float bvv[2];
#pragma unroll
    for (int t = 0; t < 2; ++t) {
        const _Float16* a = pl0 + (16*t + q)*STRD;
        float s = fin[8];
#pragma unroll
        for (int e = 0; e < 8; ++e) s = fmaf(fin[e], (float)a[e], s);
        bvv[t] = s;
    }

    // ---- A1: 1->64 relu on VALU, written in C-layout positions ------------
#pragma unroll
    for (int t = 0; t < 2; ++t) {
        const int grow = row0 + 16*t + q;
        const float xa = x[grow * NP + p];
#pragma unroll
        for (int Mt = 0; Mt < 4; ++Mt) {
            const f32x4 w4 = *(const f32x4*)(g_a1w[p] + (Mt*64 + l)*4);
            const f32x4 b4 = *(const f32x4*)(g_a1b[p] + (Mt*64 + l)*4);
            f16x4 o4;
#pragma unroll
            for (int j = 0; j < 4; ++j)
                o4[j] = (_Float16)fmaxf(fmaf(w4[j], xa, b4[j]), 0.0f);
            *(f16x4*)(pl1 + (16*t + q)*STRD + 16*Mt + 4*g) = o4;
        }
    }
    read_bf<2>(pl1, bf, q, g);
    // A2: 64->32 tanh
    mfma_block<2,2,2,false>(frag, bias, 12, 10, bf, pl0, q, g, l);
    read_bf<1>(pl0, bf, q, g);
    // A3: 32->16 tanh (+zero-pad)
    mfma_block<1,1,2,true >(frag, bias, 16, 12, bf, pl1, q, g, l);
    read_bf<1>(pl1, bf, q, g);
    // A4: 16->8 tanh
    mfma_block<1,1,2,false>(frag, bias, 17, 13, bf, pl0, q, g, l);

    // A5: 8->1 + interleaved store (a,b) by lane-group 0
#pragma unroll
    for (int t = 0; t < 2; ++t) {
        const _Float16* a = pl0 + (16*t + q)*STRD;
        float s = fin[17];
#pragma unroll
        for (int e = 0; e < 8; ++e) s = fmaf(fin[9 + e], (float)a[e], s);
        if (g == 0) {
            const int grow = row0 + 16*t + q;
            reinterpret_cast<float2*>(out)[(size_t)grow * NP + p] =
                make_float2(s, bvv[t]);
        }
    }
}

extern "C" void kernel_launch(void* const* d_in, const int* in_sizes, int n_in,
                              void* d_out, int out_size, void* d_ws,
                              size_t ws_size, hipStream_t stream) {
    const float* x   = (const float*)d_in[0];
    const float* Wa1 = (const float*)d_in[1];
    const float* ba1 = (const float*)d_in[2];
    const float* Wa2 = (const float*)d_in[3];
    const float* ba2 = (const float*)d_in[4];
    const float* Wa3 = (const float*)d_in[5];
    const float* ba3 = (const float*)d_in[6];
    const float* Wa4 = (const float*)d_in[7];
    const float* ba4 = (const float*)d_in[8];
    const float* Wa5 = (const float*)d_in[9];
    const float* ba5 = (const float*)d_in[10];
    const float* Wb1 = (const float*)d_in[11];
    const float* bb1 = (const float*)d_in[12];
    const float* Wb2 = (const float*)d_in[13];
    const float* bb2 = (const float*)d_in[14];
    const float* Wb3 = (const float*)d_in[15];
    const float* bb3 = (const float*)d_in[16];
    const float* Wb4 = (const float*)d_in[17];
    const float* bb4 = (const float*)d_in[18];
    const float* Wb5 = (const float*)d_in[19];
    const float* bb5 = (const float*)d_in[20];
    const float* Wb6 = (const float*)d_in[21];
    const float* bb6 = (const float*)d_in[22];

    prep_frags<<<dim3(NP), dim3(64), 0, stream>>>(
        Wa1, ba1, Wa2, ba2, Wa3, ba3, Wa4, ba4, Wa5, ba5,
        Wb1, bb1, Wb2, bb2, Wb3, bb3, Wb4, bb4, Wb5, bb5, Wb6, bb6);

    dim3 grid(NROWS / 128, NP);
    mlp_mfma<<<grid, 256, 0, stream>>>(x, (float*)d_out);
}

// Round 7
// 278.895 us; speedup vs baseline: 3.3861x; 1.0836x over previous
//
#include <hip/hip_runtime.h>

#define NP 32
#define NROWS 65536

typedef _Float16 f16x8 __attribute__((ext_vector_type(8)));
typedef _Float16 f16x4 __attribute__((ext_vector_type(4)));
typedef _Float16 f16x2 __attribute__((ext_vector_type(2)));
typedef __fp16   fp16x2 __attribute__((ext_vector_type(2)));
typedef float    f32x4 __attribute__((ext_vector_type(4)));

#if __has_builtin(__builtin_amdgcn_rcpf)
#define FAST_RCP(x) __builtin_amdgcn_rcpf(x)
#else
#define FAST_RCP(x) (1.0f / (x))
#endif

// tanh(x) = 1 - 2/(e^{2x}+1). No clamp needed: e->inf gives 1, e->0 gives -1.
__device__ __forceinline__ float fast_tanh(float v) {
    float e = __expf(2.0f * v);
    return fmaf(-2.0f, FAST_RCP(e + 1.0f), 1.0f);
}

// v_cvt_pkrtz_f16_f32 returns __fp16x2; bit_cast to our _Float16 vectors.
__device__ __forceinline__ f16x4 pack4(float c0, float c1, float c2, float c3) {
    const f16x2 p01 = __builtin_bit_cast(f16x2, __builtin_amdgcn_cvt_pkrtz(c0, c1));
    const f16x2 p23 = __builtin_bit_cast(f16x2, __builtin_amdgcn_cvt_pkrtz(c2, c3));
    return __builtin_shufflevector(p01, p23, 0, 1, 2, 3);
}

// ---------------- prepacked weight storage (device globals) ----------------
// 17 MFMA steps per p: B1:s0-3 (bias folded into k=31 col, input=1)
//   B2:s4-7  B3:s8-9  B4:s10  A2:s11-14  A3:s15  A4:s16   (order: Mt, ks)
// A-frag layout: A[row=lane&15][k=8*(lane>>4)+e]; C: out=16Mt+4*(l>>4)+j, n=l&15.
// 9 bias steps (C-layout): B2:0-1 B3:2-3 B4:4 A2:5-6 A3:7 A4:8
__device__ __align__(16) _Float16 g_frag[NP][17 * 2 * 64 * 8]; // hi/lo pairs
__device__ __align__(16) float    g_bias[NP][9 * 64 * 4];
__device__ __align__(16) float    g_a1w [NP][4 * 64 * 4];
__device__ __align__(16) float    g_a1b [NP][4 * 64 * 4];
// fin: [0..15]=W56 (Wb6·Wb5 folded), [16]=b56, [17..24]=Wa5, [25]=ba5
__device__ __align__(16) float    g_fin [NP][32];

__global__ void prep_frags(
    const float* __restrict__ Wa1, const float* __restrict__ ba1,
    const float* __restrict__ Wa2, const float* __restrict__ ba2,
    const float* __restrict__ Wa3, const float* __restrict__ ba3,
    const float* __restrict__ Wa4, const float* __restrict__ ba4,
    const float* __restrict__ Wa5, const float* __restrict__ ba5,
    const float* __restrict__ Wb1, const float* __restrict__ bb1,
    const float* __restrict__ Wb2, const float* __restrict__ bb2,
    const float* __restrict__ Wb3, const float* __restrict__ bb3,
    const float* __restrict__ Wb4, const float* __restrict__ bb4,
    const float* __restrict__ Wb5, const float* __restrict__ bb5,
    const float* __restrict__ Wb6, const float* __restrict__ bb6) {
    const int p = blockIdx.x;
    const int l = threadIdx.x;          // 0..63
    const int g = l >> 4, q = l & 15;

    const int sw[17]  = {0,0,0,0, 1,1,1,1, 2,2, 3, 4,4,4,4, 5, 6};
    const int sMt[17] = {0,1,2,3, 0,0,1,1, 0,1, 0, 0,0,1,1, 0, 0};
    const int sks[17] = {0,0,0,0, 0,1,0,1, 0,0, 0, 0,1,0,1, 0, 0};
    const int OO[7] = {64,32,32,16,32,16, 8};
    const int II[7] = {31,64,32,32,64,32,16};
    const float* WS[7] = {Wb1 + p*1984, Wb2 + p*2048, Wb3 + p*1024,
                          Wb4 + p*512,  Wa2 + p*2048, Wa3 + p*512,
                          Wa4 + p*128};
    const float* b1s = bb1 + p*64;
    for (int s = 0; s < 17; ++s) {
        const int w = sw[s], O = OO[w], I = II[w];
        const float* W = WS[s < 4 ? 0 : w];
        for (int e = 0; e < 8; ++e) {
            const int kk = 32*sks[s] + 8*g + e;   // K index
            const int o  = 16*sMt[s] + q;         // out (= A row)
            float wv = 0.0f;
            if (o < O) {
                if (w == 0)  // B1: col 31 carries the bias (input slot = 1.0)
                    wv = (kk < 31) ? W[o*31 + kk] : (kk == 31 ? b1s[o] : 0.0f);
                else
                    wv = (kk < I) ? W[o*I + kk] : 0.0f;
            }
            const _Float16 hi = (_Float16)wv;
            const _Float16 lo = (_Float16)(wv - (float)hi);
            g_frag[p][((s*2 + 0)*64 + l)*8 + e] = hi;
            g_frag[p][((s*2 + 1)*64 + l)*8 + e] = lo;
        }
    }
    const int bw[9]  = {0,0, 1,1, 2, 3,3, 4, 5};
    const int bMt[9] = {0,1, 0,1, 0, 0,1, 0, 0};
    const float* BS[6] = {bb2 + p*32, bb3 + p*32, bb4 + p*16,
                          ba2 + p*32, ba3 + p*16, ba4 + p*8};
    const int BO[6] = {32,32,16,32,16,8};
    for (int bs = 0; bs < 9; ++bs) {
        const int w = bw[bs];
        for (int j = 0; j < 4; ++j) {
            const int o = 16*bMt[bs] + 4*g + j;
            g_bias[p][(bs*64 + l)*4 + j] = (o < BO[w]) ? BS[w][o] : 0.0f;
        }
    }
    for (int Mt = 0; Mt < 4; ++Mt)
        for (int j = 0; j < 4; ++j) {
            const int o = 16*Mt + 4*g + j;
            g_a1w[p][(Mt*64 + l)*4 + j] = Wa1[p*64 + o];
            g_a1b[p][(Mt*64 + l)*4 + j] = ba1[p*64 + o];
        }
    if (l == 0) {
        // fold B5 (16->8) and B6 (8->1): W56 = Wb6·Wb5, b56 = Wb6·bb5 + bb6
        for (int i = 0; i < 16; ++i) {
            float s = 0.0f;
            for (int o = 0; o < 8; ++o)
                s += Wb6[p*8 + o] * Wb5[p*128 + o*16 + i];
            g_fin[p][i] = s;
        }
        float s = bb6[p];
        for (int o = 0; o < 8; ++o) s += Wb6[p*8 + o] * bb5[p*8 + o];
        g_fin[p][16] = s;
        for (int e = 0; e < 8; ++e) g_fin[p][17 + e] = Wa5[p*8 + e];
        g_fin[p][25] = ba5[p];
    }
}

// ---------------- main kernel ----------------------------------------------
// Wave = 32 rows (2 tiles of 16), acts ping-pong between a wide (64-col) and
// a narrow (32-col) private LDS plane. No barriers (wave-private slices).
#define S0 68   // wide plane stride (halves)
#define S1 36   // narrow plane stride

template <int KS, int SSTR>
__device__ __forceinline__ void read_bf(const _Float16* src, f16x8 (&bf)[2][2],
                                        int q, int g) {
#pragma unroll
    for (int t = 0; t < 2; ++t)
#pragma unroll
        for (int ks = 0; ks < KS; ++ks) {
            const _Float16* a = src + (16*t + q)*SSTR + 32*ks + 8*g;
            const f16x4 v0 = *(const f16x4*)(a);
            const f16x4 v1 = *(const f16x4*)(a + 4);
            bf[t][ks] = __builtin_shufflevector(v0, v1, 0,1,2,3,4,5,6,7);
        }
}

// C[out=16Mt+4g+j][n=16t+q] += (Whi+Wlo)·B ; bias+act -> dst plane (f16)
template <int MT, int KS, int ACT, bool ZPAD, bool HASBIAS, int DSTR>
__device__ __forceinline__ void mfma_block(const _Float16* __restrict__ frag,
                                           const float* __restrict__ bias,
                                           int s0, int b0,
                                           const f16x8 (&bf)[2][2],
                                           _Float16* dst, int q, int g, int l) {
#pragma unroll
    for (int Mt = 0; Mt < MT; ++Mt) {
        f32x4 a0 = {0.f,0.f,0.f,0.f}, a1 = {0.f,0.f,0.f,0.f};
#pragma unroll
        for (int ks = 0; ks < KS; ++ks) {
            const int s = s0 + Mt*KS + ks;
            const f16x8 whi = *(const f16x8*)(frag + ((s*2 + 0)*64 + l)*8);
            const f16x8 wlo = *(const f16x8*)(frag + ((s*2 + 1)*64 + l)*8);
            a0 = __builtin_amdgcn_mfma_f32_16x16x32_f16(wlo, bf[0][ks], a0, 0,0,0);
            a0 = __builtin_amdgcn_mfma_f32_16x16x32_f16(whi, bf[0][ks], a0, 0,0,0);
            a1 = __builtin_amdgcn_mfma_f32_16x16x32_f16(wlo, bf[1][ks], a1, 0,0,0);
            a1 = __builtin_amdgcn_mfma_f32_16x16x32_f16(whi, bf[1][ks], a1, 0,0,0);
        }
        f32x4 b4 = {0.f,0.f,0.f,0.f};
        if (HASBIAS) b4 = *(const f32x4*)(bias + ((b0 + Mt)*64 + l)*4);
#pragma unroll
        for (int t = 0; t < 2; ++t) {
            const f32x4 av = t ? a1 : a0;
            float c[4];
#pragma unroll
            for (int j = 0; j < 4; ++j) {
                float v = HASBIAS ? (av[j] + b4[j]) : av[j];
                if (ACT == 1) v = fmaxf(v, 0.0f);
                if (ACT == 2) v = fast_tanh(v);
                c[j] = v;
            }
            const f16x4 o4 = pack4(c[0], c[1], c[2], c[3]);
            *(f16x4*)(dst + (16*t + q)*DSTR + 16*Mt + 4*g) = o4;
        }
    }
    if (ZPAD) {   // zero k=16..31 so next layer can read a padded K=32
        const f16x4 z = {(_Float16)0, (_Float16)0, (_Float16)0, (_Float16)0};
#pragma unroll
        for (int t = 0; t < 2; ++t)
            *(f16x4*)(dst + (16*t + q)*DSTR + 16 + 4*g) = z;
    }
}

__global__ __launch_bounds__(256, 6) void mlp_mfma(
    const float* __restrict__ x, float* __restrict__ out) {
    __shared__ __align__(16) _Float16 lds0[4][32 * S0];  // wide plane
    __shared__ __align__(16) _Float16 lds1[4][32 * S1];  // narrow plane

    // Block remap: consecutive dispatch -> same XCD p-octets for one row
    // chunk, so partial 8B output writes into a 64B line merge in that
    // XCD's L2 (round-5: 162 MB HBM writes = 10x output size).
    const int L   = blockIdx.x;          // 0..16383
    const int xcd = L & 7;
    const int m   = L >> 3;
    const int p   = m & 31;              // feature
    const int rc  = xcd + 8 * (m >> 5);  // row chunk 0..511
    const int wv  = threadIdx.x >> 6;
    const int l   = threadIdx.x & 63;
    const int g   = l >> 4, q = l & 15;
    const int row0 = rc * 128 + wv * 32;

    _Float16* pl0 = lds0[wv];
    _Float16* pl1 = lds1[wv];
    const _Float16* frag = g_frag[p];
    const float*    bias = g_bias[p];
    const float*    fin  = g_fin[p];

    f16x8 bf[2][2];

    // ---- B1 B-frag from x: leave-one-out, k=31 slot = 1.0 (bias column) ---
#pragma unroll
    for (int t = 0; t < 2; ++t) {
        const int grow = row0 + 16*t + q;
        const float* xr = x + grow * NP;
#pragma unroll
        for (int e = 0; e < 8; ++e) {
            const int k = 8*g + e;
            const float xv = (k < 31) ? xr[k + (k >= p ? 1 : 0)] : 1.0f;
            bf[t][0][e] = (_Float16)xv;
        }
    }
    // B1: 31->64 relu (bias folded)
    mfma_block<4,1,1,false,false,S0>(frag, bias,  0, 0, bf, pl0, q, g, l);
    read_bf<2, S0>(pl0, bf, q, g);
    // B2: 64->32 tanh
    mfma_block<2,2,2,false,true, S1>(frag, bias,  4, 0, bf, pl1, q, g, l);
    read_bf<1, S1>(pl1, bf, q, g);
    // B3: 32->32 tanh
    mfma_block<2,1,2,false,true, S0>(frag, bias,  8, 2, bf, pl0, q, g, l);
    read_bf<1, S0>(pl0, bf, q, g);
    // B4: 32->16 tanh
    mfma_block<1,1,2,false,true, S1>(frag, bias, 10, 4, bf, pl1, q, g, l);

    // B5+B6 folded: 16->1 dot on VALU
    float bvv[2];
#pragma unroll
    for (int t = 0; t < 2; ++t) {
        const _Float16* a = pl1 + (16*t + q)*S1;
        float s = fin[16];
#pragma unroll
        for (int e = 0; e < 16; ++e) s = fmaf(fin[e], (float)a[e], s);
        bvv[t] = s;
    }

    // ---- A1: 1->64 relu on VALU, written in C-layout positions ------------
#pragma unroll
    for (int t = 0; t < 2; ++t) {
        const int grow = row0 + 16*t + q;
        const float xa = x[grow * NP + p];
#pragma unroll
        for (int Mt = 0; Mt < 4; ++Mt) {
            const f32x4 w4 = *(const f32x4*)(g_a1w[p] + (Mt*64 + l)*4);
            const f32x4 b4 = *(const f32x4*)(g_a1b[p] + (Mt*64 + l)*4);
            float c[4];
#pragma unroll
            for (int j = 0; j < 4; ++j)
                c[j] = fmaxf(fmaf(w4[j], xa, b4[j]), 0.0f);
            const f16x4 o4 = pack4(c[0], c[1], c[2], c[3]);
            *(f16x4*)(pl0 + (16*t + q)*S0 + 16*Mt + 4*g) = o4;
        }
    }
    read_bf<2, S0>(pl0, bf, q, g);
    // A2: 64->32 tanh
    mfma_block<2,2,2,false,true, S1>(frag, bias, 11, 5, bf, pl1, q, g, l);
    read_bf<1, S1>(pl1, bf, q, g);
    // A3: 32->16 tanh (+zero-pad K to 32)
    mfma_block<1,1,2,true, true, S0>(frag, bias, 15, 7, bf, pl0, q, g, l);
    read_bf<1, S0>(pl0, bf, q, g);
    // A4: 16->8 tanh
    mfma_block<1,1,2,false,true, S1>(frag, bias, 16, 8, bf, pl1, q, g, l);

    // A5: 8->1 dot + interleaved (a,b) store by lane-group 0
#pragma unroll
    for (int t = 0; t < 2; ++t) {
        const _Float16* a = pl1 + (16*t + q)*S1;
        float s = fin[25];
#pragma unroll
        for (int e = 0; e < 8; ++e) s = fmaf(fin[17 + e], (float)a[e], s);
        if (g == 0) {
            const int grow = row0 + 16*t + q;
            reinterpret_cast<float2*>(out)[(size_t)grow * NP + p] =
                make_float2(s, bvv[t]);
        }
    }
}

extern "C" void kernel_launch(void* const* d_in, const int* in_sizes, int n_in,
                              void* d_out, int out_size, void* d_ws,
                              size_t ws_size, hipStream_t stream) {
    const float* x   = (const float*)d_in[0];
    const float* Wa1 = (const float*)d_in[1];
    const float* ba1 = (const float*)d_in[2];
    const float* Wa2 = (const float*)d_in[3];
    const float* ba2 = (const float*)d_in[4];
    const float* Wa3 = (const float*)d_in[5];
    const float* ba3 = (const float*)d_in[6];
    const float* Wa4 = (const float*)d_in[7];
    const float* ba4 = (const float*)d_in[8];
    const float* Wa5 = (const float*)d_in[9];
    const float* ba5 = (const float*)d_in[10];
    const float* Wb1 = (const float*)d_in[11];
    const float* bb1 = (const float*)d_in[12];
    const float* Wb2 = (const float*)d_in[13];
    const float* bb2 = (const float*)d_in[14];
    const float* Wb3 = (const float*)d_in[15];
    const float* bb3 = (const float*)d_in[16];
    const float* Wb4 = (const float*)d_in[17];
    const float* bb4 = (const float*)d_in[18];
    const float* Wb5 = (const float*)d_in[19];
    const float* bb5 = (const float*)d_in[20];
    const float* Wb6 = (const float*)d_in[21];
    const float* bb6 = (const float*)d_in[22];

    prep_frags<<<dim3(NP), dim3(64), 0, stream>>>(
        Wa1, ba1, Wa2, ba2, Wa3, ba3, Wa4, ba4, Wa5, ba5,
        Wb1, bb1, Wb2, bb2, Wb3, bb3, Wb4, bb4, Wb5, bb5, Wb6, bb6);

    mlp_mfma<<<dim3(NROWS / 128 * NP), 256, 0, stream>>>(x, (float*)d_out);
}

// Round 8
// 254.600 us; speedup vs baseline: 3.7092x; 1.0954x over previous
//
#include <hip/hip_runtime.h>

#define NP 32
#define NROWS 65536

typedef _Float16 f16x8 __attribute__((ext_vector_type(8)));
typedef _Float16 f16x4 __attribute__((ext_vector_type(4)));
typedef _Float16 f16x2 __attribute__((ext_vector_type(2)));
typedef float    f32x4 __attribute__((ext_vector_type(4)));

#if __has_builtin(__builtin_amdgcn_rcpf)
#define FAST_RCP(x) __builtin_amdgcn_rcpf(x)
#else
#define FAST_RCP(x) (1.0f / (x))
#endif

// tanh(x) = 1 - 2/(e^{2x}+1). No clamp needed: e->inf gives 1, e->0 gives -1.
__device__ __forceinline__ float fast_tanh(float v) {
    float e = __expf(2.0f * v);
    return fmaf(-2.0f, FAST_RCP(e + 1.0f), 1.0f);
}

// v_cvt_pkrtz_f16_f32 returns __fp16x2; bit_cast to our _Float16 vectors.
__device__ __forceinline__ f16x4 pack4(float c0, float c1, float c2, float c3) {
    const f16x2 p01 = __builtin_bit_cast(f16x2, __builtin_amdgcn_cvt_pkrtz(c0, c1));
    const f16x2 p23 = __builtin_bit_cast(f16x2, __builtin_amdgcn_cvt_pkrtz(c2, c3));
    return __builtin_shufflevector(p01, p23, 0, 1, 2, 3);
}

// ---------------- prepacked weight storage (device globals) ----------------
// 17 MFMA steps per p: B1:s0-3 (bias folded into k=31 col, input=1)
//   B2:s4-7  B3:s8-9  B4:s10  A2:s11-14  A3:s15  A4:s16   (order: Mt, ks)
// A-frag layout: A[row=lane&15][k=8*(lane>>4)+e]; C: out=16Mt+4*(l>>4)+j, n=l&15.
// 9 bias steps (C-layout): B2:0-1 B3:2-3 B4:4 A2:5-6 A3:7 A4:8
__device__ __align__(16) _Float16 g_frag[NP][17 * 2 * 64 * 8]; // hi/lo pairs
__device__ __align__(16) float    g_bias[NP][9 * 64 * 4];
__device__ __align__(16) float    g_a1w [NP][4 * 64 * 4];
__device__ __align__(16) float    g_a1b [NP][4 * 64 * 4];
// fin: [0..15]=W56 (Wb6·Wb5 folded), [16]=b56, [17..24]=Wa5, [25]=ba5
__device__ __align__(16) float    g_fin [NP][32];

__global__ void prep_frags(
    const float* __restrict__ Wa1, const float* __restrict__ ba1,
    const float* __restrict__ Wa2, const float* __restrict__ ba2,
    const float* __restrict__ Wa3, const float* __restrict__ ba3,
    const float* __restrict__ Wa4, const float* __restrict__ ba4,
    const float* __restrict__ Wa5, const float* __restrict__ ba5,
    const float* __restrict__ Wb1, const float* __restrict__ bb1,
    const float* __restrict__ Wb2, const float* __restrict__ bb2,
    const float* __restrict__ Wb3, const float* __restrict__ bb3,
    const float* __restrict__ Wb4, const float* __restrict__ bb4,
    const float* __restrict__ Wb5, const float* __restrict__ bb5,
    const float* __restrict__ Wb6, const float* __restrict__ bb6) {
    const int p = blockIdx.x;
    const int l = threadIdx.x;          // 0..63
    const int g = l >> 4, q = l & 15;

    const int sw[17]  = {0,0,0,0, 1,1,1,1, 2,2, 3, 4,4,4,4, 5, 6};
    const int sMt[17] = {0,1,2,3, 0,0,1,1, 0,1, 0, 0,0,1,1, 0, 0};
    const int sks[17] = {0,0,0,0, 0,1,0,1, 0,0, 0, 0,1,0,1, 0, 0};
    const int OO[7] = {64,32,32,16,32,16, 8};
    const int II[7] = {31,64,32,32,64,32,16};
    const float* WS[7] = {Wb1 + p*1984, Wb2 + p*2048, Wb3 + p*1024,
                          Wb4 + p*512,  Wa2 + p*2048, Wa3 + p*512,
                          Wa4 + p*128};
    const float* b1s = bb1 + p*64;
    for (int s = 0; s < 17; ++s) {
        const int w = sw[s], O = OO[w], I = II[w];
        const float* W = WS[w];
        for (int e = 0; e < 8; ++e) {
            const int kk = 32*sks[s] + 8*g + e;   // K index
            const int o  = 16*sMt[s] + q;         // out (= A row)
            float wv = 0.0f;
            if (o < O) {
                if (w == 0)  // B1: col 31 carries the bias (input slot = 1.0)
                    wv = (kk < 31) ? W[o*31 + kk] : (kk == 31 ? b1s[o] : 0.0f);
                else
                    wv = (kk < I) ? W[o*I + kk] : 0.0f;
            }
            const _Float16 hi = (_Float16)wv;
            const _Float16 lo = (_Float16)(wv - (float)hi);
            g_frag[p][((s*2 + 0)*64 + l)*8 + e] = hi;
            g_frag[p][((s*2 + 1)*64 + l)*8 + e] = lo;
        }
    }
    const int bw[9]  = {0,0, 1,1, 2, 3,3, 4, 5};
    const int bMt[9] = {0,1, 0,1, 0, 0,1, 0, 0};
    const float* BS[6] = {bb2 + p*32, bb3 + p*32, bb4 + p*16,
                          ba2 + p*32, ba3 + p*16, ba4 + p*8};
    const int BO[6] = {32,32,16,32,16,8};
    for (int bs = 0; bs < 9; ++bs) {
        const int w = bw[bs];
        for (int j = 0; j < 4; ++j) {
            const int o = 16*bMt[bs] + 4*g + j;
            g_bias[p][(bs*64 + l)*4 + j] = (o < BO[w]) ? BS[w][o] : 0.0f;
        }
    }
    for (int Mt = 0; Mt < 4; ++Mt)
        for (int j = 0; j < 4; ++j) {
            const int o = 16*Mt + 4*g + j;
            g_a1w[p][(Mt*64 + l)*4 + j] = Wa1[p*64 + o];
            g_a1b[p][(Mt*64 + l)*4 + j] = ba1[p*64 + o];
        }
    if (l == 0) {
        // fold B5 (16->8) and B6 (8->1): W56 = Wb6·Wb5, b56 = Wb6·bb5 + bb6
        for (int i = 0; i < 16; ++i) {
            float s = 0.0f;
            for (int o = 0; o < 8; ++o)
                s += Wb6[p*8 + o] * Wb5[p*128 + o*16 + i];
            g_fin[p][i] = s;
        }
        float s = bb6[p];
        for (int o = 0; o < 8; ++o) s += Wb6[p*8 + o] * bb5[p*8 + o];
        g_fin[p][16] = s;
        for (int e = 0; e < 8; ++e) g_fin[p][17 + e] = Wa5[p*8 + e];
        g_fin[p][25] = ba5[p];
    }
}

// ---------------- main kernel ----------------------------------------------
// Wave = 64 rows (4 tiles of 16) for 4-way MFMA/epilogue ILP and 2x frag-load
// amortization (round 7 was latency-bound at VGPR=40: no pipelining room).
// Single wave-private LDS plane; in-order DS + waitcnt makes read->write-same-
// rows safe. No barriers anywhere.
#define S0 68   // plane stride (halves); 64 cols + 4 pad

template <int KS>
__device__ __forceinline__ void read_bf(const _Float16* src, f16x8 (&bf)[4][2],
                                        int q, int g) {
#pragma unroll
    for (int t = 0; t < 4; ++t)
#pragma unroll
        for (int ks = 0; ks < KS; ++ks) {
            const _Float16* a = src + (16*t + q)*S0 + 32*ks + 8*g;
            const f16x4 v0 = *(const f16x4*)(a);
            const f16x4 v1 = *(const f16x4*)(a + 4);
            bf[t][ks] = __builtin_shufflevector(v0, v1, 0,1,2,3,4,5,6,7);
        }
}

// C[out=16Mt+4g+j][n=16t+q] += (Whi+Wlo)·B ; bias+act -> dst plane (f16)
template <int MT, int KS, int ACT, bool ZPAD, bool HASBIAS>
__device__ __forceinline__ void mfma_block(const _Float16* __restrict__ frag,
                                           const float* __restrict__ bias,
                                           int s0, int b0,
                                           const f16x8 (&bf)[4][2],
                                           _Float16* dst, int q, int g, int l) {
#pragma unroll
    for (int Mt = 0; Mt < MT; ++Mt) {
        f32x4 a[4];
#pragma unroll
        for (int t = 0; t < 4; ++t) a[t] = f32x4{0.f,0.f,0.f,0.f};
#pragma unroll
        for (int ks = 0; ks < KS; ++ks) {
            const int s = s0 + Mt*KS + ks;
            const f16x8 whi = *(const f16x8*)(frag + ((s*2 + 0)*64 + l)*8);
            const f16x8 wlo = *(const f16x8*)(frag + ((s*2 + 1)*64 + l)*8);
#pragma unroll
            for (int t = 0; t < 4; ++t) {
                a[t] = __builtin_amdgcn_mfma_f32_16x16x32_f16(wlo, bf[t][ks], a[t], 0,0,0);
                a[t] = __builtin_amdgcn_mfma_f32_16x16x32_f16(whi, bf[t][ks], a[t], 0,0,0);
            }
        }
        f32x4 b4 = {0.f,0.f,0.f,0.f};
        if (HASBIAS) b4 = *(const f32x4*)(bias + ((b0 + Mt)*64 + l)*4);
#pragma unroll
        for (int t = 0; t < 4; ++t) {
            float c[4];
#pragma unroll
            for (int j = 0; j < 4; ++j) {
                float v = HASBIAS ? (a[t][j] + b4[j]) : a[t][j];
                if (ACT == 1) v = fmaxf(v, 0.0f);
                if (ACT == 2) v = fast_tanh(v);
                c[j] = v;
            }
            const f16x4 o4 = pack4(c[0], c[1], c[2], c[3]);
            *(f16x4*)(dst + (16*t + q)*S0 + 16*Mt + 4*g) = o4;
        }
    }
    if (ZPAD) {   // zero k=16..31 so next layer can read a padded K=32
        const f16x4 z = {(_Float16)0, (_Float16)0, (_Float16)0, (_Float16)0};
#pragma unroll
        for (int t = 0; t < 4; ++t)
            *(f16x4*)(dst + (16*t + q)*S0 + 16 + 4*g) = z;
    }
}

__global__ __launch_bounds__(256, 4) void mlp_mfma(
    const float* __restrict__ x, float* __restrict__ out) {
    __shared__ __align__(16) _Float16 lds[4][64 * S0];  // 34816 B/block

    // Block remap: the 32 p-blocks of one row chunk are consecutive on the
    // same XCD so partial 8B output writes merge in that XCD's L2
    // (round 7 verified: WRITE_SIZE 162 -> 16.4 MB).
    const int L   = blockIdx.x;          // 0..8191
    const int xcd = L & 7;
    const int m   = L >> 3;
    const int p   = m & 31;              // feature
    const int rc  = xcd + 8 * (m >> 5);  // row chunk 0..255
    const int wv  = threadIdx.x >> 6;
    const int l   = threadIdx.x & 63;
    const int g   = l >> 4, q = l & 15;
    const int row0 = rc * 256 + wv * 64;

    _Float16* pl = lds[wv];
    const _Float16* frag = g_frag[p];
    const float*    bias = g_bias[p];
    const float*    fin  = g_fin[p];

    f16x8 bf[4][2];

    // ---- B1 B-frag from x: leave-one-out, k=31 slot = 1.0 (bias column) ---
#pragma unroll
    for (int t = 0; t < 4; ++t) {
        const int grow = row0 + 16*t + q;
        const float* xr = x + grow * NP;
#pragma unroll
        for (int e = 0; e < 8; ++e) {
            const int k = 8*g + e;
            const float xv = (k < 31) ? xr[k + (k >= p ? 1 : 0)] : 1.0f;
            bf[t][0][e] = (_Float16)xv;
        }
    }
    // B1: 31->64 relu (bias folded)
    mfma_block<4,1,1,false,false>(frag, bias,  0, 0, bf, pl, q, g, l);
    read_bf<2>(pl, bf, q, g);
    // B2: 64->32 tanh
    mfma_block<2,2,2,false,true>(frag, bias,  4, 0, bf, pl, q, g, l);
    read_bf<1>(pl, bf, q, g);
    // B3: 32->32 tanh
    mfma_block<2,1,2,false,true>(frag, bias,  8, 2, bf, pl, q, g, l);
    read_bf<1>(pl, bf, q, g);
    // B4: 32->16 tanh
    mfma_block<1,1,2,false,true>(frag, bias, 10, 4, bf, pl, q, g, l);

    // B5+B6 folded: 16->1 dot on VALU
    float bvv[4];
#pragma unroll
    for (int t = 0; t < 4; ++t) {
        const _Float16* a = pl + (16*t + q)*S0;
        float s = fin[16];
#pragma unroll
        for (int e = 0; e < 16; ++e) s = fmaf(fin[e], (float)a[e], s);
        bvv[t] = s;
    }

    // ---- A1: 1->64 relu on VALU, written in C-layout positions ------------
#pragma unroll
    for (int t = 0; t < 4; ++t) {
        const int grow = row0 + 16*t + q;
        const float xa = x[grow * NP + p];
#pragma unroll
        for (int Mt = 0; Mt < 4; ++Mt) {
            const f32x4 w4 = *(const f32x4*)(g_a1w[p] + (Mt*64 + l)*4);
            const f32x4 b4 = *(const f32x4*)(g_a1b[p] + (Mt*64 + l)*4);
            float c[4];
#pragma unroll
            for (int j = 0; j < 4; ++j)
                c[j] = fmaxf(fmaf(w4[j], xa, b4[j]), 0.0f);
            const f16x4 o4 = pack4(c[0], c[1], c[2], c[3]);
            *(f16x4*)(pl + (16*t + q)*S0 + 16*Mt + 4*g) = o4;
        }
    }
    read_bf<2>(pl, bf, q, g);
    // A2: 64->32 tanh
    mfma_block<2,2,2,false,true>(frag, bias, 11, 5, bf, pl, q, g, l);
    read_bf<1>(pl, bf, q, g);
    // A3: 32->16 tanh (+zero-pad K to 32)
    mfma_block<1,1,2,true, true>(frag, bias, 15, 7, bf, pl, q, g, l);
    read_bf<1>(pl, bf, q, g);
    // A4: 16->8 tanh
    mfma_block<1,1,2,false,true>(frag, bias, 16, 8, bf, pl, q, g, l);

    // A5: 8->1 dot + interleaved (a,b) store by lane-group 0
#pragma unroll
    for (int t = 0; t < 4; ++t) {
        const _Float16* a = pl + (16*t + q)*S0;
        float s = fin[25];
#pragma unroll
        for (int e = 0; e < 8; ++e) s = fmaf(fin[17 + e], (float)a[e], s);
        if (g == 0) {
            const int grow = row0 + 16*t + q;
            reinterpret_cast<float2*>(out)[(size_t)grow * NP + p] =
                make_float2(s, bvv[t]);
        }
    }
}

extern "C" void kernel_launch(void* const* d_in, const int* in_sizes, int n_in,
                              void* d_out, int out_size, void* d_ws,
                              size_t ws_size, hipStream_t stream) {
    const float* x   = (const float*)d_in[0];
    const float* Wa1 = (const float*)d_in[1];
    const float* ba1 = (const float*)d_in[2];
    const float* Wa2 = (const float*)d_in[3];
    const float* ba2 = (const float*)d_in[4];
    const float* Wa3 = (const float*)d_in[5];
    const float* ba3 = (const float*)d_in[6];
    const float* Wa4 = (const float*)d_in[7];
    const float* ba4 = (const float*)d_in[8];
    const float* Wa5 = (const float*)d_in[9];
    const float* ba5 = (const float*)d_in[10];
    const float* Wb1 = (const float*)d_in[11];
    const float* bb1 = (const float*)d_in[12];
    const float* Wb2 = (const float*)d_in[13];
    const float* bb2 = (const float*)d_in[14];
    const float* Wb3 = (const float*)d_in[15];
    const float* bb3 = (const float*)d_in[16];
    const float* Wb4 = (const float*)d_in[17];
    const float* bb4 = (const float*)d_in[18];
    const float* Wb5 = (const float*)d_in[19];
    const float* bb5 = (const float*)d_in[20];
    const float* Wb6 = (const float*)d_in[21];
    const float* bb6 = (const float*)d_in[22];

    prep_frags<<<dim3(NP), dim3(64), 0, stream>>>(
        Wa1, ba1, Wa2, ba2, Wa3, ba3, Wa4, ba4, Wa5, ba5,
        Wb1, bb1, Wb2, bb2, Wb3, bb3, Wb4, bb4, Wb5, bb5, Wb6, bb6);

    mlp_mfma<<<dim3(NROWS / 256 * NP), 256, 0, stream>>>(x, (float*)d_out);
}